// Round 1
// baseline (111.451 us; speedup 1.0000x reference)
//
#include <hip/hip_runtime.h>
#include <math.h>

namespace {

constexpr int S = 100;
constexpr int NR = 800;
constexpr int RPB = 8;           // batch rows per block
constexpr int NTH = 512;         // 8 waves
constexpr int IN_COLS = 2 + S;   // 102
constexpr int OUT_COLS = 3 + NR + 2 + S; // 905
constexpr float RGASF = 8314.46261815324f;
constexpr float ATMF = 101325.0f;

__device__ __forceinline__ float wave_sum(float v) {
#pragma unroll
  for (int off = 32; off; off >>= 1) v += __shfl_xor(v, off);
  return v;
}

__global__ __launch_bounds__(NTH)
void chem_props_kernel(const float* __restrict__ TPY,
                       const float* __restrict__ mw,
                       const float* __restrict__ nasa_low,
                       const float* __restrict__ nasa_high,
                       const float* __restrict__ eff,
                       const float* __restrict__ i3b,
                       const float* __restrict__ visc_poly,
                       const float* __restrict__ cond_poly,
                       const float* __restrict__ bdiff_poly,
                       float* __restrict__ out)
{
  __shared__ __align__(16) float Xl[S][RPB];     // mole fractions
  __shared__ __align__(16) float u1l[S][RPB];    // X / sqrt(visc)
  __shared__ __align__(16) float u2l[S][RPB];    // X / visc
  __shared__ __align__(16) float viscl[S][RPB];
  __shared__ __align__(16) float svl[S][RPB];    // sqrt(visc)
  __shared__ __align__(16) float denoml[S][RPB];
  __shared__ __align__(16) float xjdl[S][RPB];
  __shared__ float mwl[S], imwl[S];
  __shared__ float rs_L[RPB], rs_cfac[RPB], rs_mW[RPB], rs_scale[RPB];
  __shared__ float vsum[RPB];

  const int tid = threadIdx.x;
  const int wid = tid >> 6;    // wave id == row in tile
  const int lane = tid & 63;
  const int row0 = blockIdx.x * RPB;
  const int rowg = row0 + wid;

  // zero the atomic accumulators
  for (int idx = tid; idx < S * RPB; idx += NTH) {
    (&denoml[0][0])[idx] = 0.0f;
    (&xjdl[0][0])[idx] = 0.0f;
  }
  if (tid < RPB) vsum[tid] = 0.0f;
  if (tid < S) {
    float m = mw[tid];
    mwl[tid] = m;
    imwl[tid] = 1.0f / m;
  }
  __syncthreads();

  // ============ Stage A: per-row scalars/species (one wave per row) ========
  {
    const float* rowp = TPY + (size_t)rowg * IN_COLS;
    float T = fmaxf(rowp[0], 200.0f);
    float P = rowp[1];
    float L = logf(T);
    float T2 = T * T, T3 = T2 * T, T4 = T2 * T2;
    float invT = 1.0f / T;

    int sA = lane, sB = lane + 64;
    bool hasB = (sB < S);
    float y0 = fmaxf(rowp[2 + sA], 0.0f);
    float y1 = hasB ? fmaxf(rowp[2 + sB], 0.0f) : 0.0f;
    float im0 = imwl[sA];
    float im1 = hasB ? imwl[sB] : 0.0f;

    float ysum = wave_sum(y0 + y1);
    float invy = 1.0f / ysum;
    float sw = wave_sum(y0 * im0 + y1 * im1) * invy; // sum Ynorm/mw
    float mW = 1.0f / sw;
    float cfac = P / (RGASF * T);                    // C = X * cfac
    float lnP = logf(P * (1.0f / ATMF));

    const float* nasa = (T <= 1000.0f) ? nasa_low : nasa_high;

    float cpx = 0.0f, hy = 0.0f, sy = 0.0f, condA = 0.0f, condB = 0.0f;
#pragma unroll
    for (int t = 0; t < 2; ++t) {
      int s = (t == 0) ? sA : sB;
      if (s < S) {
        float yn = ((t == 0) ? y0 : y1) * invy;
        float im = (t == 0) ? im0 : im1;
        float x = fmaxf(yn * mW * im, 1e-12f);
        const float* a = nasa + s * 7;
        float a0 = a[0], a1 = a[1], a2 = a[2], a3 = a[3],
              a4 = a[4], a5 = a[5], a6 = a[6];
        float cp = a0 + a1 * T + a2 * T2 + a3 * T3 + a4 * T4;
        float Ht = a0 + 0.5f * a1 * T + (1.0f / 3.0f) * a2 * T2
                 + 0.25f * a3 * T3 + 0.2f * a4 * T4 + a5 * invT;
        float S0r = a0 * L + a1 * T + 0.5f * a2 * T2
                  + (1.0f / 3.0f) * a3 * T3 + 0.25f * a4 * T4 + a6;
        cpx += cp * x;
        hy += Ht * im * yn;
        sy += (S0r - logf(x) - lnP) * im * yn;

        float v = visc_poly[0 * S + s];
        v = fmaf(v, L, visc_poly[1 * S + s]);
        v = fmaf(v, L, visc_poly[2 * S + s]);
        v = fmaf(v, L, visc_poly[3 * S + s]);
        v = fmaf(v, L, visc_poly[4 * S + s]);
        float c = cond_poly[0 * S + s];
        c = fmaf(c, L, cond_poly[1 * S + s]);
        c = fmaf(c, L, cond_poly[2 * S + s]);
        c = fmaf(c, L, cond_poly[3 * S + s]);
        c = fmaf(c, L, cond_poly[4 * S + s]);
        condA += x * c;
        condB += x / c;
        float sv = sqrtf(v);
        Xl[s][wid] = x;
        viscl[s][wid] = v;
        svl[s][wid] = sv;
        u1l[s][wid] = x / sv;
        u2l[s][wid] = x / v;
      }
    }
    float scp = wave_sum(cpx);
    float sh = wave_sum(hy);
    float ss = wave_sum(sy);
    float sca = wave_sum(condA);
    float scb = wave_sum(condB);
    if (lane == 0) {
      float* orow = out + (size_t)rowg * OUT_COLS;
      orow[0] = RGASF * scp;                 // cp_mole
      orow[1] = RGASF * T * sh;              // enthalpy_mass
      orow[2] = RGASF * ss;                  // entropy_mass
      orow[3 + NR + 1] = 0.5f * (sca + 1.0f / scb); // thermal_conductivity
      rs_L[wid] = L;
      rs_cfac[wid] = cfac;
      rs_mW[wid] = mW;
      rs_scale[wid] = ATMF / (mW * P);
    }
  }
  __syncthreads();

  // ============ Stage B: C_M2 = (C @ eff)*i3b + (1-i3b) ====================
  for (int q = tid; q < NR; q += NTH) {
    float acc[RPB];
#pragma unroll
    for (int b = 0; b < RPB; ++b) acc[b] = 0.0f;
    for (int s = 0; s < S; ++s) {
      float e = eff[s * NR + q];
      float xv[RPB];
      *(float4*)&xv[0] = *(const float4*)&Xl[s][0];
      *(float4*)&xv[4] = *(const float4*)&Xl[s][4];
#pragma unroll
      for (int b = 0; b < RPB; ++b) acc[b] = fmaf(xv[b], e, acc[b]);
    }
    float t3 = i3b[q];
    float base = 1.0f - t3;
#pragma unroll
    for (int b = 0; b < RPB; ++b) {
      float cm = acc[b] * rs_cfac[b];
      out[(size_t)(row0 + b) * OUT_COLS + 3 + q] = fmaf(cm, t3, base);
    }
  }

  // ============ Stage C1: viscosity mixing denominators ====================
  // denom[b][i] = sum_k A(i,k)X + 2*sv_i*(A*B4)(X/sv) + visc_i*(A*B4^2)(X/visc)
  if (tid < 500) {
    const int i = tid % 100;
    const int kg = tid / 100;          // 5 k-groups of 20
    const float mwi = mwl[i];
    const float imwi = imwl[i];
    float d0[RPB], d1[RPB], d2[RPB];
#pragma unroll
    for (int b = 0; b < RPB; ++b) { d0[b] = 0; d1[b] = 0; d2[b] = 0; }
    const int k0 = kg * 20;
    for (int k = k0; k < k0 + 20; ++k) {
      float mwk = mwl[k];
      float A = 0.35355339059327373f *
                __builtin_amdgcn_rsqf(1.0f + mwi * imwl[k]);
      float B4 = sqrtf(sqrtf(mwk * imwi));
      float m1 = A * B4, m2 = m1 * B4;
      float xv[RPB], u1v[RPB], u2v[RPB];
      *(float4*)&xv[0] = *(const float4*)&Xl[k][0];
      *(float4*)&xv[4] = *(const float4*)&Xl[k][4];
      *(float4*)&u1v[0] = *(const float4*)&u1l[k][0];
      *(float4*)&u1v[4] = *(const float4*)&u1l[k][4];
      *(float4*)&u2v[0] = *(const float4*)&u2l[k][0];
      *(float4*)&u2v[4] = *(const float4*)&u2l[k][4];
#pragma unroll
      for (int b = 0; b < RPB; ++b) {
        d0[b] = fmaf(A, xv[b], d0[b]);
        d1[b] = fmaf(m1, u1v[b], d1[b]);
        d2[b] = fmaf(m2, u2v[b], d2[b]);
      }
    }
#pragma unroll
    for (int b = 0; b < RPB; ++b) {
      float pden = d0[b] + 2.0f * svl[i][b] * d1[b] + viscl[i][b] * d2[b];
      atomicAdd(&denoml[i][b], pden);
    }
  }
  __syncthreads();

  // ============ Stage C2: viscosity sum | Stage D1: XjDjk ==================
  if (tid < 800) {
    const int i = tid % 100;
    const int b = tid / 100;
    float contrib = Xl[i][b] * viscl[i][b] / denoml[i][b];
    atomicAdd(&vsum[b], contrib);
  }
  if (tid < 500) {
    const int k = tid % 100;
    const int jg = tid / 100;
    float Lb[RPB];
#pragma unroll
    for (int b = 0; b < RPB; ++b) Lb[b] = rs_L[b];
    float acc[RPB];
#pragma unroll
    for (int b = 0; b < RPB; ++b) acc[b] = 0.0f;
    const int j0 = jg * 20;
    for (int j = j0; j < j0 + 20; ++j) {
      if (j == k) continue;  // diagonal cancels exactly in the reference
      float c0 = bdiff_poly[0 * 10000 + j * 100 + k];
      float c1 = bdiff_poly[1 * 10000 + j * 100 + k];
      float c2 = bdiff_poly[2 * 10000 + j * 100 + k];
      float c3 = bdiff_poly[3 * 10000 + j * 100 + k];
      float c4 = bdiff_poly[4 * 10000 + j * 100 + k];
      float xv[RPB];
      *(float4*)&xv[0] = *(const float4*)&Xl[j][0];
      *(float4*)&xv[4] = *(const float4*)&Xl[j][4];
#pragma unroll
      for (int b = 0; b < RPB; ++b) {
        float p = fmaf(c0, Lb[b], c1);
        p = fmaf(p, Lb[b], c2);
        p = fmaf(p, Lb[b], c3);
        p = fmaf(p, Lb[b], c4);
        acc[b] = fmaf(xv[b], __builtin_amdgcn_rcpf(p), acc[b]);
      }
    }
#pragma unroll
    for (int b = 0; b < RPB; ++b) atomicAdd(&xjdl[k][b], acc[b]);
  }
  __syncthreads();

  // ============ Final writes ==============================================
  if (tid < RPB) {
    out[(size_t)(row0 + tid) * OUT_COLS + 3 + NR] = vsum[tid]; // viscosities
  }
  if (tid < 800) {
    const int k = tid % 100;
    const int b = tid / 100;
    float num = rs_mW[b] - Xl[k][b] * mwl[k];        // XjWj
    float md = num / xjdl[k][b] * rs_scale[b];       // mix_diff
    out[(size_t)(row0 + b) * OUT_COLS + 3 + NR + 2 + k] = md;
  }
}

} // namespace

extern "C" void kernel_launch(void* const* d_in, const int* in_sizes, int n_in,
                              void* d_out, int out_size, void* d_ws, size_t ws_size,
                              hipStream_t stream) {
  const float* TPY        = (const float*)d_in[0];
  const float* mwp        = (const float*)d_in[1];
  const float* nasa_low   = (const float*)d_in[2];
  const float* nasa_high  = (const float*)d_in[3];
  const float* eff        = (const float*)d_in[4];
  const float* i3b        = (const float*)d_in[5];
  const float* visc_poly  = (const float*)d_in[6];
  const float* cond_poly  = (const float*)d_in[7];
  const float* bdiff_poly = (const float*)d_in[8];
  float* out = (float*)d_out;

  const int B = 2048;
  dim3 grid(B / RPB);
  chem_props_kernel<<<grid, NTH, 0, stream>>>(
      TPY, mwp, nasa_low, nasa_high, eff, i3b,
      visc_poly, cond_poly, bdiff_poly, out);
}

// Round 2
// 105.395 us; speedup vs baseline: 1.0575x; 1.0575x over previous
//
#include <hip/hip_runtime.h>
#include <math.h>

namespace {

constexpr int S = 100;
constexpr int NR = 800;
constexpr int RPB = 4;           // batch rows per block
constexpr int NTH = 512;         // 8 waves
constexpr int IN_COLS = 2 + S;   // 102
constexpr int OUT_COLS = 3 + NR + 2 + S; // 905
constexpr float RGASF = 8314.46261815324f;
constexpr float ATMF = 101325.0f;

__device__ __forceinline__ float wave_sum(float v) {
#pragma unroll
  for (int off = 32; off; off >>= 1) v += __shfl_xor(v, off);
  return v;
}

__global__ __launch_bounds__(NTH)
void chem_props_kernel(const float* __restrict__ TPY,
                       const float* __restrict__ mw,
                       const float* __restrict__ nasa_low,
                       const float* __restrict__ nasa_high,
                       const float* __restrict__ eff,
                       const float* __restrict__ i3b,
                       const float* __restrict__ visc_poly,
                       const float* __restrict__ cond_poly,
                       const float* __restrict__ bdiff_poly,
                       float* __restrict__ out)
{
  __shared__ __align__(16) float Xl[S][RPB];     // mole fractions
  __shared__ __align__(16) float u1l[S][RPB];    // X / sqrt(visc)
  __shared__ __align__(16) float u2l[S][RPB];    // X / visc
  __shared__ __align__(16) float viscl[S][RPB];
  __shared__ __align__(16) float svl[S][RPB];    // sqrt(visc)
  __shared__ __align__(16) float denoml[S][RPB];
  __shared__ __align__(16) float xjdl[S][RPB];
  __shared__ float mwl[S], imwl[S];
  __shared__ float pa[8][2];                     // phase-1 partials (y, y/mw)
  __shared__ float pb[8][5];                     // phase-2 partials
  __shared__ float rs_L[RPB], rs_cfac[RPB], rs_mW[RPB], rs_scale[RPB], rs_T[RPB];
  __shared__ float vsum[RPB];

  const int tid = threadIdx.x;
  const int wid = tid >> 6;
  const int lane = tid & 63;
  const int row0 = blockIdx.x * RPB;

  // zero the accumulators
  for (int idx = tid; idx < S * RPB; idx += NTH) {
    (&denoml[0][0])[idx] = 0.0f;
    (&xjdl[0][0])[idx] = 0.0f;
  }
  if (tid < RPB) vsum[tid] = 0.0f;
  if (tid < S) {
    float m = mw[tid];
    mwl[tid] = m;
    imwl[tid] = 1.0f / m;
  }
  __syncthreads();

  // ============ Stage A: per-row species (2 waves per row) =================
  {
    const int row = wid & 3;            // row in tile
    const int half = wid >> 2;          // species half: 0 -> 0..63, 1 -> 64..99
    const int rowg = row0 + row;
    const float* rowp = TPY + (size_t)rowg * IN_COLS;
    float T = fmaxf(rowp[0], 200.0f);
    float P = rowp[1];
    float L = __logf(T);
    float T2 = T * T, T3 = T2 * T, T4 = T2 * T2;
    float invT = 1.0f / T;

    int s = half * 64 + lane;
    bool valid = (s < S);
    float y = valid ? fmaxf(rowp[2 + s], 0.0f) : 0.0f;
    float im = valid ? imwl[s] : 0.0f;

    float py = wave_sum(y);
    float pw = wave_sum(y * im);
    if (lane == 0) { pa[wid][0] = py; pa[wid][1] = pw; }
    __syncthreads();
    float ysum = pa[row][0] + pa[row + 4][0];
    float wsum = pa[row][1] + pa[row + 4][1];
    float invy = 1.0f / ysum;
    float mW = ysum / wsum;                          // 1 / sum(Ynorm/mw)
    float cfac = P / (RGASF * T);
    float lnP = __logf(P * (1.0f / ATMF));

    const float* nasa = (T <= 1000.0f) ? nasa_low : nasa_high;

    float cpx = 0.0f, hy = 0.0f, sy = 0.0f, condA = 0.0f, condB = 0.0f;
    if (valid) {
      float yn = y * invy;
      float x = fmaxf(yn * mW * im, 1e-12f);
      const float* a = nasa + s * 7;
      float a0 = a[0], a1 = a[1], a2 = a[2], a3 = a[3],
            a4 = a[4], a5 = a[5], a6 = a[6];
      float cp = a0 + a1 * T + a2 * T2 + a3 * T3 + a4 * T4;
      float Ht = a0 + 0.5f * a1 * T + (1.0f / 3.0f) * a2 * T2
               + 0.25f * a3 * T3 + 0.2f * a4 * T4 + a5 * invT;
      float S0r = a0 * L + a1 * T + 0.5f * a2 * T2
                + (1.0f / 3.0f) * a3 * T3 + 0.25f * a4 * T4 + a6;
      cpx = cp * x;
      hy = Ht * im * yn;
      sy = (S0r - __logf(x) - lnP) * im * yn;

      float v = visc_poly[0 * S + s];
      v = fmaf(v, L, visc_poly[1 * S + s]);
      v = fmaf(v, L, visc_poly[2 * S + s]);
      v = fmaf(v, L, visc_poly[3 * S + s]);
      v = fmaf(v, L, visc_poly[4 * S + s]);
      float c = cond_poly[0 * S + s];
      c = fmaf(c, L, cond_poly[1 * S + s]);
      c = fmaf(c, L, cond_poly[2 * S + s]);
      c = fmaf(c, L, cond_poly[3 * S + s]);
      c = fmaf(c, L, cond_poly[4 * S + s]);
      condA = x * c;
      condB = x / c;
      float sv = sqrtf(v);
      Xl[s][row] = x;
      viscl[s][row] = v;
      svl[s][row] = sv;
      u1l[s][row] = x / sv;
      u2l[s][row] = x / v;
    }
    float scp = wave_sum(cpx);
    float sh = wave_sum(hy);
    float ss = wave_sum(sy);
    float sca = wave_sum(condA);
    float scb = wave_sum(condB);
    if (lane == 0) {
      pb[wid][0] = scp; pb[wid][1] = sh; pb[wid][2] = ss;
      pb[wid][3] = sca; pb[wid][4] = scb;
      if (half == 0) {
        rs_L[row] = L;
        rs_T[row] = T;
        rs_cfac[row] = cfac;
        rs_mW[row] = mW;
        rs_scale[row] = ATMF / (mW * P);
      }
    }
  }
  __syncthreads();

  if (tid < RPB) {
    const int row = tid;
    float scp = pb[row][0] + pb[row + 4][0];
    float sh  = pb[row][1] + pb[row + 4][1];
    float ss  = pb[row][2] + pb[row + 4][2];
    float sca = pb[row][3] + pb[row + 4][3];
    float scb = pb[row][4] + pb[row + 4][4];
    float* orow = out + (size_t)(row0 + row) * OUT_COLS;
    orow[0] = RGASF * scp;
    orow[1] = RGASF * rs_T[row] * sh;
    orow[2] = RGASF * ss;
    orow[3 + NR + 1] = 0.5f * (sca + 1.0f / scb);
  }

  // ============ Stage B: C_M2 = (C @ eff)*i3b + (1-i3b), float2 q ==========
  if (tid < 400) {
    const int q0 = 2 * tid;
    float acc[2 * RPB];
#pragma unroll
    for (int b = 0; b < 2 * RPB; ++b) acc[b] = 0.0f;
#pragma unroll 4
    for (int s = 0; s < S; ++s) {
      float2 e = *(const float2*)&eff[s * NR + q0];
      float xv[RPB];
      *(float4*)&xv[0] = *(const float4*)&Xl[s][0];
#pragma unroll
      for (int b = 0; b < RPB; ++b) {
        acc[b] = fmaf(xv[b], e.x, acc[b]);
        acc[RPB + b] = fmaf(xv[b], e.y, acc[RPB + b]);
      }
    }
    float2 t3 = *(const float2*)&i3b[q0];
    float base0 = 1.0f - t3.x, base1 = 1.0f - t3.y;
#pragma unroll
    for (int b = 0; b < RPB; ++b) {
      float cf = rs_cfac[b];
      float* op = out + (size_t)(row0 + b) * OUT_COLS + 3 + q0;
      op[0] = fmaf(acc[b] * cf, t3.x, base0);
      op[1] = fmaf(acc[RPB + b] * cf, t3.y, base1);
    }
  }

  // ============ Stage C1: viscosity mixing denominators ====================
  if (tid < 500) {
    const int i = tid % 100;
    const int kg = tid / 100;          // 5 k-groups of 20
    const float mwi = mwl[i];
    const float imwi = imwl[i];
    float d0[RPB], d1[RPB], d2[RPB];
#pragma unroll
    for (int b = 0; b < RPB; ++b) { d0[b] = 0; d1[b] = 0; d2[b] = 0; }
    const int k0 = kg * 20;
#pragma unroll 2
    for (int k = k0; k < k0 + 20; ++k) {
      float mwk = mwl[k];
      float A = 0.35355339059327373f *
                __builtin_amdgcn_rsqf(1.0f + mwi * imwl[k]);
      float B4 = sqrtf(sqrtf(mwk * imwi));
      float m1 = A * B4, m2 = m1 * B4;
      float xv[RPB], u1v[RPB], u2v[RPB];
      *(float4*)&xv[0] = *(const float4*)&Xl[k][0];
      *(float4*)&u1v[0] = *(const float4*)&u1l[k][0];
      *(float4*)&u2v[0] = *(const float4*)&u2l[k][0];
#pragma unroll
      for (int b = 0; b < RPB; ++b) {
        d0[b] = fmaf(A, xv[b], d0[b]);
        d1[b] = fmaf(m1, u1v[b], d1[b]);
        d2[b] = fmaf(m2, u2v[b], d2[b]);
      }
    }
#pragma unroll
    for (int b = 0; b < RPB; ++b) {
      float pden = d0[b] + 2.0f * svl[i][b] * d1[b] + viscl[i][b] * d2[b];
      atomicAdd(&denoml[i][b], pden);
    }
  }
  __syncthreads();

  // ============ Stage C2: viscosity sum | Stage D1: XjDjk ==================
  if (tid < 100 * RPB) {
    const int i = tid % 100;
    const int b = tid / 100;
    float contrib = Xl[i][b] * viscl[i][b] / denoml[i][b];
    atomicAdd(&vsum[b], contrib);
  }
  if (tid < 500) {
    const int k = tid % 100;
    const int jg = tid / 100;
    float Lb[RPB];
#pragma unroll
    for (int b = 0; b < RPB; ++b) Lb[b] = rs_L[b];
    float acc[RPB];
#pragma unroll
    for (int b = 0; b < RPB; ++b) acc[b] = 0.0f;
    const int j0 = jg * 20;
#pragma unroll 2
    for (int j = j0; j < j0 + 20; ++j) {
      if (j == k) continue;  // diagonal cancels exactly in the reference
      float c0 = bdiff_poly[0 * 10000 + j * 100 + k];
      float c1 = bdiff_poly[1 * 10000 + j * 100 + k];
      float c2 = bdiff_poly[2 * 10000 + j * 100 + k];
      float c3 = bdiff_poly[3 * 10000 + j * 100 + k];
      float c4 = bdiff_poly[4 * 10000 + j * 100 + k];
      float xv[RPB];
      *(float4*)&xv[0] = *(const float4*)&Xl[j][0];
#pragma unroll
      for (int b = 0; b < RPB; ++b) {
        float p = fmaf(c0, Lb[b], c1);
        p = fmaf(p, Lb[b], c2);
        p = fmaf(p, Lb[b], c3);
        p = fmaf(p, Lb[b], c4);
        acc[b] = fmaf(xv[b], __builtin_amdgcn_rcpf(p), acc[b]);
      }
    }
#pragma unroll
    for (int b = 0; b < RPB; ++b) atomicAdd(&xjdl[k][b], acc[b]);
  }
  __syncthreads();

  // ============ Final writes ==============================================
  if (tid < RPB) {
    out[(size_t)(row0 + tid) * OUT_COLS + 3 + NR] = vsum[tid]; // viscosities
  }
  if (tid < 100 * RPB) {
    const int k = tid % 100;
    const int b = tid / 100;
    float num = rs_mW[b] - Xl[k][b] * mwl[k];        // XjWj
    float md = num / xjdl[k][b] * rs_scale[b];       // mix_diff
    out[(size_t)(row0 + b) * OUT_COLS + 3 + NR + 2 + k] = md;
  }
}

} // namespace

extern "C" void kernel_launch(void* const* d_in, const int* in_sizes, int n_in,
                              void* d_out, int out_size, void* d_ws, size_t ws_size,
                              hipStream_t stream) {
  const float* TPY        = (const float*)d_in[0];
  const float* mwp        = (const float*)d_in[1];
  const float* nasa_low   = (const float*)d_in[2];
  const float* nasa_high  = (const float*)d_in[3];
  const float* eff        = (const float*)d_in[4];
  const float* i3b        = (const float*)d_in[5];
  const float* visc_poly  = (const float*)d_in[6];
  const float* cond_poly  = (const float*)d_in[7];
  const float* bdiff_poly = (const float*)d_in[8];
  float* out = (float*)d_out;

  const int B = 2048;
  dim3 grid(B / RPB);
  chem_props_kernel<<<grid, NTH, 0, stream>>>(
      TPY, mwp, nasa_low, nasa_high, eff, i3b,
      visc_poly, cond_poly, bdiff_poly, out);
}